// Round 3
// baseline (457.145 us; speedup 1.0000x reference)
//
#include <hip/hip_runtime.h>
#include <cstdint>

// ---------------------------------------------------------------------------
// GroupedQueryAttention: B=2 N=2048 DIM=2048 HQ=16 HKV=4 HD=128, causal, RoPE.
// ALL I/O tensors are float32 (npz-size evidence, round 2). Internals bf16.
// Pipeline: sincos -> QKV proj GEMMs (f32 in, bf16 out) -> RoPE -> V transpose
//           -> flash attention -> O proj GEMM (bf16 in, f32 out).
// GEMM staging: reg-staged with inline f32->bf16 convert, XOR-swizzled LDS.
// ---------------------------------------------------------------------------

typedef __bf16 bf16_t;
typedef __attribute__((ext_vector_type(8))) __bf16 bf16x8;
typedef __attribute__((ext_vector_type(4))) float f32x4;

#define B_    2
#define N_    2048
#define DIM_  2048
#define HQ_   16
#define HKV_  4
#define HD_   128
#define KVD_  512
#define SCALE_ 0.08838834764831845f  // 128^-0.5

// ---------------------------------------------------------------------------
// cos/sin table: [2048][64] each, f32.  inv_freq = 10000^(-i/64) (base_adj==1)
// ---------------------------------------------------------------------------
__global__ void k_sincos(float* __restrict__ cosT, float* __restrict__ sinT) {
  int idx = blockIdx.x * 256 + threadIdx.x;  // 2048*64
  int i = idx & 63;
  int n = idx >> 6;
  float inv = expf(-(float)i * (9.210340371976184f / 64.0f));  // ln(1e4)/64
  float ang = (float)n * inv;
  cosT[idx] = cosf(ang);
  sinT[idx] = sinf(ang);
}

// ---------------------------------------------------------------------------
// C = A @ W^T + bias.  A:[M][K] (f32 if AF32 else bf16), W:[N][K] f32,
// C:[M][N] (f32 if CF32 else bf16).  Dual-issue via blockIdx.z.
// 128x128 tile, BK=64, 4 waves each 64x64. LDS bf16 [128][64], XOR swizzle.
// ---------------------------------------------------------------------------
template <bool AF32, bool CF32>
__global__ __launch_bounds__(256, 2) void k_gemm_bt(
    const void* __restrict__ A0v, const float* __restrict__ W0,
    const float* __restrict__ b0, void* __restrict__ C0v,
    const void* __restrict__ A1v, const float* __restrict__ W1,
    const float* __restrict__ b1, void* __restrict__ C1v,
    int M, int N, int K)
{
  const void* Av = A0v; const float* W = W0;
  const float* bias = b0; void* Cv = C0v;
  if (blockIdx.z == 1) { Av = A1v; W = W1; bias = b1; Cv = C1v; }

  __shared__ bf16_t As[128 * 64];
  __shared__ bf16_t Bs[128 * 64];
  const int tid  = threadIdx.x;
  const int lane = tid & 63;
  const int wave = tid >> 6;
  const int l15  = lane & 15;
  const int lg   = lane >> 4;
  const int bm = blockIdx.x, bn = blockIdx.y;
  const int wr = (wave >> 1) * 64, wc = (wave & 1) * 64;

  f32x4 acc[4][4] = {};

  uint8_t* AsB = (uint8_t*)As;
  uint8_t* BsB = (uint8_t*)Bs;

  for (int k0 = 0; k0 < K; k0 += 64) {
    // stage: 128 rows x 64 cols per tile = 1024 8-elem chunks, 256 thr x 4
    for (int i = 0; i < 4; ++i) {
      int c = i * 256 + tid;
      int row = c >> 3;            // 0..127
      int k8  = (c & 7) * 8;       // element offset within K-tile
      bf16x8 va, vb;
      if (AF32) {
        const float* ap = (const float*)Av + (size_t)(bm * 128 + row) * K + k0 + k8;
        f32x4 alo = *(const f32x4*)ap;
        f32x4 ahi = *(const f32x4*)(ap + 4);
        va[0] = (bf16_t)alo[0]; va[1] = (bf16_t)alo[1];
        va[2] = (bf16_t)alo[2]; va[3] = (bf16_t)alo[3];
        va[4] = (bf16_t)ahi[0]; va[5] = (bf16_t)ahi[1];
        va[6] = (bf16_t)ahi[2]; va[7] = (bf16_t)ahi[3];
      } else {
        va = *(const bf16x8*)((const bf16_t*)Av + (size_t)(bm * 128 + row) * K + k0 + k8);
      }
      {
        const float* wp = W + (size_t)(bn * 128 + row) * K + k0 + k8;
        f32x4 wlo = *(const f32x4*)wp;
        f32x4 whi = *(const f32x4*)(wp + 4);
        vb[0] = (bf16_t)wlo[0]; vb[1] = (bf16_t)wlo[1];
        vb[2] = (bf16_t)wlo[2]; vb[3] = (bf16_t)wlo[3];
        vb[4] = (bf16_t)whi[0]; vb[5] = (bf16_t)whi[1];
        vb[6] = (bf16_t)whi[2]; vb[7] = (bf16_t)whi[3];
      }
      int sw = (k8 * 2) ^ ((row & 7) << 4);
      *(bf16x8*)(AsB + row * 128 + sw) = va;
      *(bf16x8*)(BsB + row * 128 + sw) = vb;
    }
    __syncthreads();
    for (int kk = 0; kk < 2; ++kk) {
      const int koff = kk * 64 + (lg << 4);
      bf16x8 fa[4], fb[4];
      for (int fi = 0; fi < 4; ++fi) {
        int row = wr + fi * 16 + l15;
        fa[fi] = *(const bf16x8*)(AsB + row * 128 + (koff ^ ((row & 7) << 4)));
      }
      for (int fj = 0; fj < 4; ++fj) {
        int row = wc + fj * 16 + l15;
        fb[fj] = *(const bf16x8*)(BsB + row * 128 + (koff ^ ((row & 7) << 4)));
      }
      for (int fi = 0; fi < 4; ++fi)
        for (int fj = 0; fj < 4; ++fj)
          acc[fi][fj] = __builtin_amdgcn_mfma_f32_16x16x32_bf16(
              fa[fi], fb[fj], acc[fi][fj], 0, 0, 0);
    }
    __syncthreads();
  }

  // epilogue: C/D layout col=lane&15, row=(lane>>4)*4+r
  const int r0 = lg * 4;
  for (int fi = 0; fi < 4; ++fi) {
    for (int rr = 0; rr < 4; ++rr) {
      int grow = bm * 128 + wr + fi * 16 + r0 + rr;
      size_t rowoff = (size_t)grow * N;
      for (int fj = 0; fj < 4; ++fj) {
        int gcol = bn * 128 + wc + fj * 16 + l15;
        float v = acc[fi][fj][rr] + bias[gcol];
        if (CF32) ((float*)Cv)[rowoff + gcol] = v;
        else      ((bf16_t*)Cv)[rowoff + gcol] = (bf16_t)v;
      }
    }
  }
}

// ---------------------------------------------------------------------------
// RoPE in-place on X:[4096][nheads*128] bf16.  lgnh = log2(nheads). outScale
// folds the attention softmax scale into Q.
// ---------------------------------------------------------------------------
__global__ void k_rope(bf16_t* __restrict__ X, const float* __restrict__ cosT,
                       const float* __restrict__ sinT, int lgnh, float outScale)
{
  int idx = blockIdx.x * 256 + threadIdx.x;
  int d = idx & 63;
  int h = (idx >> 6) & ((1 << lgnh) - 1);
  int row = idx >> (6 + lgnh);
  int n = row & (N_ - 1);
  float c = cosT[(n << 6) + d];
  float s = sinT[(n << 6) + d];
  size_t base = (size_t)row * (size_t)(128 << lgnh) + (h << 7) + d;
  float x1 = (float)X[base];
  float x2 = (float)X[base + 64];
  X[base]      = (bf16_t)((x1 * c - x2 * s) * outScale);
  X[base + 64] = (bf16_t)((x2 * c + x1 * s) * outScale);
}

// ---------------------------------------------------------------------------
// Vp:[4096][512] -> Vt:[B*HKV][128][2048]  (Vt[bh][d][n] = Vp[b*2048+n][hkv*128+d])
// ---------------------------------------------------------------------------
__global__ void k_transpose_v(const bf16_t* __restrict__ Vp, bf16_t* __restrict__ Vt)
{
  __shared__ bf16_t tile[64][72];
  const int tid = threadIdx.x;
  const int r0 = blockIdx.x * 64;  // global row (b*2048+n)
  const int d0 = blockIdx.y * 64;  // col in [0,512)
  for (int r = 0; r < 2; ++r) {
    int n = r * 32 + (tid >> 3);
    int dc = (tid & 7) * 8;
    *(uint4*)&tile[n][dc] = *(const uint4*)(Vp + (size_t)(r0 + n) * KVD_ + d0 + dc);
  }
  __syncthreads();
  const int b = r0 >> 11;
  const int nseq = r0 & (N_ - 1);
  for (int r = 0; r < 2; ++r) {
    int dd = r * 32 + (tid >> 3);
    int nc = (tid & 7) * 8;
    int dglob = d0 + dd;
    int hkv = dglob >> 7, dloc = dglob & 127;
    union { bf16_t h[8]; uint4 v; } pk;
    for (int j = 0; j < 8; ++j) pk.h[j] = tile[nc + j][dd];
    size_t drow = (size_t)(b * HKV_ + hkv) * 128 + dloc;
    *(uint4*)(Vt + drow * N_ + nseq + nc) = pk.v;
  }
}

// ---------------------------------------------------------------------------
// Flash attention, causal GQA. Block = (qblk, b*16+hq). 4 waves x 16 queries.
// K tile [64][128] and V^T tile [128][64] reg-staged swizzled; P via LDS.
// ---------------------------------------------------------------------------
__global__ __launch_bounds__(256, 2) void k_attn(
    const bf16_t* __restrict__ Qp, const bf16_t* __restrict__ Kp,
    const bf16_t* __restrict__ Vt, bf16_t* __restrict__ AO)
{
  __shared__ bf16_t Ks[64 * 128];
  __shared__ bf16_t Vs[128 * 64];
  __shared__ bf16_t Ps[4][16 * 72];
  const int tid = threadIdx.x, lane = tid & 63, wave = tid >> 6;
  const int l15 = lane & 15, lg = lane >> 4;
  const int qblk = blockIdx.x;
  const int bh = blockIdx.y;
  const int b = bh >> 4, hq = bh & 15, hkv = hq >> 2;

  // Q fragments: 16 rows of this wave, K-dim 128 -> 4 mfma k-steps
  bf16x8 qf[4];
  {
    size_t qrow = (size_t)b * N_ + qblk * 64 + wave * 16 + l15;
    const uint8_t* qb = (const uint8_t*)Qp + (qrow * DIM_ + (size_t)hq * HD_) * 2 + lg * 16;
    for (int ks = 0; ks < 4; ++ks)
      qf[ks] = *(const bf16x8*)(qb + ks * 64);
  }

  float m[4]  = {-1e30f, -1e30f, -1e30f, -1e30f};
  float ln[4] = {0.f, 0.f, 0.f, 0.f};
  f32x4 o[8] = {};

  uint8_t* KsB = (uint8_t*)Ks;
  uint8_t* VsB = (uint8_t*)Vs;
  const uint8_t* KpB = (const uint8_t*)Kp + ((size_t)b * N_ * KVD_ + (size_t)hkv * HD_) * 2;
  const uint8_t* VtB = (const uint8_t*)Vt + (size_t)(b * HKV_ + hkv) * HD_ * (size_t)N_ * 2;

  for (int t = 0; t <= qblk; ++t) {
    // stage K tile: 64 rows x 256B = 1024 16B-chunks, reg-staged swizzled
    for (int i = 0; i < 4; ++i) {
      int c = i * 256 + tid;
      int row = c >> 4;
      int cby = (c & 15) * 16;
      bf16x8 v = *(const bf16x8*)(KpB + (size_t)(t * 64 + row) * (KVD_ * 2) + cby);
      *(bf16x8*)(KsB + row * 256 + (cby ^ ((row & 7) << 4))) = v;
    }
    // stage V^T tile: 128 rows x 128B
    for (int i = 0; i < 4; ++i) {
      int c = i * 256 + tid;
      int dd = c >> 3;
      int cby = (c & 7) * 16;
      bf16x8 v = *(const bf16x8*)(VtB + (size_t)dd * (N_ * 2) + t * 128 + cby);
      *(bf16x8*)(VsB + dd * 128 + (cby ^ ((dd & 7) << 4))) = v;
    }
    __syncthreads();

    // S = Q K^T : 4 col-blocks x 4 k-steps
    f32x4 s4[4] = {};
    for (int ks = 0; ks < 4; ++ks) {
      int koff = ks * 64 + (lg << 4);
      for (int cb = 0; cb < 4; ++cb) {
        int srow = cb * 16 + l15;
        bf16x8 kf = *(const bf16x8*)(KsB + srow * 256 + (koff ^ ((srow & 7) << 4)));
        s4[cb] = __builtin_amdgcn_mfma_f32_16x16x32_bf16(qf[ks], kf, s4[cb], 0, 0, 0);
      }
    }

    // causal mask (only the diagonal tile)
    if (t == qblk) {
      int rowq = wave * 16 + lg * 4;
      for (int cb = 0; cb < 4; ++cb) {
        int col = cb * 16 + l15;
        for (int rr = 0; rr < 4; ++rr)
          if (col > rowq + rr) s4[cb][rr] = -1e30f;
      }
    }

    // online softmax (row ops across the 16-lane group via shfl_xor)
    float p[4][4];
    float sc[4];
    for (int rr = 0; rr < 4; ++rr) {
      float rm = fmaxf(fmaxf(s4[0][rr], s4[1][rr]), fmaxf(s4[2][rr], s4[3][rr]));
      rm = fmaxf(rm, __shfl_xor(rm, 1));
      rm = fmaxf(rm, __shfl_xor(rm, 2));
      rm = fmaxf(rm, __shfl_xor(rm, 4));
      rm = fmaxf(rm, __shfl_xor(rm, 8));
      float mn = fmaxf(m[rr], rm);
      sc[rr] = __expf(m[rr] - mn);
      float rs = 0.f;
      for (int cb = 0; cb < 4; ++cb) {
        p[cb][rr] = __expf(s4[cb][rr] - mn);
        rs += p[cb][rr];
      }
      rs += __shfl_xor(rs, 1);
      rs += __shfl_xor(rs, 2);
      rs += __shfl_xor(rs, 4);
      rs += __shfl_xor(rs, 8);
      ln[rr] = ln[rr] * sc[rr] + rs;
      m[rr] = mn;
    }
    f32x4 sv = {sc[0], sc[1], sc[2], sc[3]};
    for (int db = 0; db < 8; ++db) o[db] *= sv;

    // P -> LDS (per-wave buffer, padded rows of 72)
    bf16_t* Pw = Ps[wave];
    for (int cb = 0; cb < 4; ++cb)
      for (int rr = 0; rr < 4; ++rr)
        Pw[(lg * 4 + rr) * 72 + cb * 16 + l15] = (bf16_t)p[cb][rr];

    // O += P @ V   (A=P from LDS, B=V^T rows from LDS)
    uint8_t* PwB = (uint8_t*)Pw;
    for (int ks2 = 0; ks2 < 2; ++ks2) {
      bf16x8 pf = *(const bf16x8*)(PwB + l15 * 144 + ks2 * 64 + (lg << 4));
      for (int db = 0; db < 8; ++db) {
        int dd = db * 16 + l15;
        bf16x8 vf = *(const bf16x8*)(VsB + dd * 128 +
                                     ((ks2 * 64 + (lg << 4)) ^ ((dd & 7) << 4)));
        o[db] = __builtin_amdgcn_mfma_f32_16x16x32_bf16(pf, vf, o[db], 0, 0, 0);
      }
    }
    __syncthreads();
  }

  // write AO[b*2048+n][hq*128+d]  (bf16)
  f32x4 inv = {1.f / ln[0], 1.f / ln[1], 1.f / ln[2], 1.f / ln[3]};
  size_t orow0 = (size_t)b * N_ + qblk * 64 + wave * 16 + lg * 4;
  for (int rr = 0; rr < 4; ++rr) {
    size_t off = (orow0 + rr) * DIM_ + (size_t)hq * HD_ + l15;
    float iv = inv[rr];
    for (int db = 0; db < 8; ++db)
      AO[off + db * 16] = (bf16_t)(o[db][rr] * iv);
  }
}

// ---------------------------------------------------------------------------
extern "C" void kernel_launch(void* const* d_in, const int* in_sizes, int n_in,
                              void* d_out, int out_size, void* d_ws, size_t ws_size,
                              hipStream_t stream)
{
  // ws layout needs 45 MB; known sufficient from round-1 signal.
  if (ws_size < (46u << 20)) return;

  const float* query = (const float*)d_in[0];
  const float* key   = (const float*)d_in[1];
  const float* value = (const float*)d_in[2];
  const float* Wq = (const float*)d_in[3];
  const float* bq = (const float*)d_in[4];
  const float* Wk = (const float*)d_in[5];
  const float* bk = (const float*)d_in[6];
  const float* Wv = (const float*)d_in[7];
  const float* bv = (const float*)d_in[8];
  const float* Wo = (const float*)d_in[9];
  const float* bo = (const float*)d_in[10];
  float* out = (float*)d_out;

  uint8_t* ws = (uint8_t*)d_ws;
  float*  cosT = (float*)(ws);                       // 512 KB
  float*  sinT = (float*)(ws + (512u << 10));        // 512 KB
  bf16_t* Qp   = (bf16_t*)(ws + (1u  << 20));        // 16 MB [4096][2048]
  bf16_t* Kp   = (bf16_t*)(ws + (17u << 20));        // 4 MB  [4096][512]
  bf16_t* Vp   = (bf16_t*)(ws + (21u << 20));        // 4 MB  [4096][512]
  bf16_t* Vt   = (bf16_t*)(ws + (25u << 20));        // 4 MB  [8][128][2048]
  bf16_t* AO   = (bf16_t*)(ws + (29u << 20));        // 16 MB [4096][2048]

  k_sincos<<<512, 256, 0, stream>>>(cosT, sinT);

  // Q projection: M=4096 N=2048 K=2048 (f32 in -> bf16 ws)
  k_gemm_bt<true, false><<<dim3(32, 16, 1), 256, 0, stream>>>(
      query, Wq, bq, Qp, query, Wq, bq, Qp, 4096, 2048, 2048);
  // K and V projections fused: M=4096 N=512 K=2048, z selects K vs V
  k_gemm_bt<true, false><<<dim3(32, 4, 2), 256, 0, stream>>>(
      key, Wk, bk, Kp, value, Wv, bv, Vp, 4096, 512, 2048);

  k_rope<<<16384, 256, 0, stream>>>(Qp, cosT, sinT, 4, SCALE_);
  k_rope<<<4096,  256, 0, stream>>>(Kp, cosT, sinT, 2, 1.0f);

  k_transpose_v<<<dim3(64, 8), 256, 0, stream>>>(Vp, Vt);

  k_attn<<<dim3(32, 32), 256, 0, stream>>>(Qp, Kp, Vt, AO);

  // Output projection: M=4096 N=2048 K=2048 (bf16 ws -> f32 out)
  k_gemm_bt<false, true><<<dim3(32, 16, 1), 256, 0, stream>>>(
      AO, Wo, bo, out, AO, Wo, bo, out, 4096, 2048, 2048);
}